// Round 11
// baseline (700.703 us; speedup 1.0000x reference)
//
#include <hip/hip_runtime.h>
#include <hip/hip_bf16.h>

// Problem constants: B=8, d=16, H=W=512, K=8
#define BB 8
#define DD 16
#define KK 8
#define NN (512 * 512)
#define G4 (NN / 4)               // 65536 float4-groups per (b,d) plane

constexpr int T    = 256;         // threads per block (4 waves)
constexpr int WV   = 4;           // waves per block
constexpr int VBPB = 128;         // k_var blocks per batch -> grid = 1024

// ws layout (floats):
#define WS_SUMS    0      // [B][K][D]  (atomics, zeroed)
#define WS_CNTS    1024   // [B][K]
#define WS_VARSUMS 1088   // [B][K]
#define WS_DUMP    1152   // ablation dump (never read, no init needed)
#define WS_TOTAL   1152   // memset only covers the real region

// ---------------- Pass 1 (REAL, identical to round 10) ----------------------
__global__ __launch_bounds__(T, 8) void k_sums(const float* __restrict__ data,
                                               const int* __restrict__ labels,
                                               float* __restrict__ ws) {
    const int e    = blockIdx.x;
    const int b    = e & 7;
    const int rem  = e >> 3;
    const int d    = rem & 15;
    const int sb   = rem >> 4;
    const int tid  = threadIdx.x;
    const int wv   = tid >> 6;
    const int lane = tid & 63;

    __shared__ float buck[T * 9];
    float* mybuck = &buck[tid * 9];
#pragma unroll
    for (int k = 0; k < KK; ++k) mybuck[k] = 0.f;

    const float4* dpl = (const float4*)(data + ((size_t)b * DD + d) * NN);
    const int4*   lp4 = (const int4*)(labels + (size_t)b * NN);
    const int gbase = sb * 4096 + wv * 1024 + lane;

    float c[KK];
#pragma unroll
    for (int k = 0; k < KK; ++k) c[k] = 0.f;

#pragma unroll 4
    for (int i = 0; i < 16; ++i) {
        const int g = gbase + i * 64;
        float4 x  = dpl[g];
        int4   lb = lp4[g];
        mybuck[lb.x] += x.x;
        mybuck[lb.y] += x.y;
        mybuck[lb.z] += x.z;
        mybuck[lb.w] += x.w;
        if (d == 0) {
            int labs[4] = {lb.x, lb.y, lb.z, lb.w};
#pragma unroll
            for (int p = 0; p < 4; ++p) {
                const int l = labs[p];
#pragma unroll
                for (int k = 0; k < KK; ++k)
                    c[k] += (l == k) ? 1.f : 0.f;
            }
        }
    }

    float s[KK];
#pragma unroll
    for (int k = 0; k < KK; ++k) s[k] = mybuck[k];
#pragma unroll
    for (int k = 0; k < KK; ++k) {
#pragma unroll
        for (int m = 1; m < 64; m <<= 1) s[k] += __shfl_xor(s[k], m, 64);
    }
    if (d == 0) {
#pragma unroll
        for (int k = 0; k < KK; ++k) {
#pragma unroll
            for (int m = 1; m < 64; m <<= 1) c[k] += __shfl_xor(c[k], m, 64);
        }
    }

    __shared__ float sred[WV][KK];
    __shared__ float cred[WV][KK];
    if (lane == 0) {
#pragma unroll
        for (int k = 0; k < KK; ++k) { sred[wv][k] = s[k]; cred[wv][k] = c[k]; }
    }
    __syncthreads();

    if (tid < KK) {
        float v = sred[0][tid] + sred[1][tid] + sred[2][tid] + sred[3][tid];
        atomicAdd(&ws[WS_SUMS + (b * KK + tid) * DD + d], v);
    } else if (d == 0 && tid >= 64 && tid < 64 + KK) {
        const int k = tid - 64;
        float v = cred[0][k] + cred[1][k] + cred[2][k] + cred[3][k];
        atomicAdd(&ws[WS_CNTS + b * KK + k], v);
    }
}

// ---------------- Pass 2 (REAL, identical to round 10) ----------------------
__global__ __launch_bounds__(T, 4) void k_var(const float* __restrict__ data,
                                              const int* __restrict__ labels,
                                              float* __restrict__ ws) {
    const int b   = blockIdx.x / VBPB;
    const int blk = blockIdx.x % VBPB;
    const int tid = threadIdx.x;

    __shared__ float cs[KK * 17 + DD];
    if (tid < KK * DD) {
        const int k = tid >> 4, d = tid & 15;
        cs[k * 17 + d] = ws[WS_SUMS + (b * KK + k) * DD + d] / ws[WS_CNTS + b * KK + k];
    }
    __syncthreads();

    const float4* dp4 = (const float4*)(data + (size_t)b * DD * NN);
    const int4*   lp4 = (const int4*)(labels + (size_t)b * NN);
    const int g0 = blk * 512 + tid;
    const int g1 = g0 + 256;

    int4 lb0 = lp4[g0];
    int4 lb1 = lp4[g1];
    int l[8] = {lb0.x, lb0.y, lb0.z, lb0.w, lb1.x, lb1.y, lb1.z, lb1.w};
    float ss[8] = {0.f, 0.f, 0.f, 0.f, 0.f, 0.f, 0.f, 0.f};

#pragma unroll 4
    for (int d = 0; d < DD; ++d) {
        const float4* pl = dp4 + (size_t)d * G4;
        float4 x0 = pl[g0];
        float4 x1 = pl[g1];
        float xs[8] = {x0.x, x0.y, x0.z, x0.w, x1.x, x1.y, x1.z, x1.w};
#pragma unroll
        for (int p = 0; p < 8; ++p) {
            float c  = cs[l[p] * 17 + d];
            float df = xs[p] - c;
            ss[p] = fmaf(df, df, ss[p]);
        }
    }

    float acc[KK];
#pragma unroll
    for (int k = 0; k < KK; ++k) acc[k] = 0.f;
#pragma unroll
    for (int p = 0; p < 8; ++p) {
        float e  = fmaxf(sqrtf(ss[p]) - 1.0f, 0.f);
        float e2 = e * e;
#pragma unroll
        for (int k = 0; k < KK; ++k) acc[k] += (l[p] == k) ? e2 : 0.f;
    }

    const int lane = tid & 63, wv = tid >> 6;
#pragma unroll
    for (int k = 0; k < KK; ++k) {
#pragma unroll
        for (int m = 1; m < 64; m <<= 1) acc[k] += __shfl_xor(acc[k], m, 64);
    }
    __shared__ float vred[WV][KK];
    if (lane == 0) {
#pragma unroll
        for (int k = 0; k < KK; ++k) vred[wv][k] = acc[k];
    }
    __syncthreads();
    if (tid < KK) {
        float v = 0.f;
#pragma unroll
        for (int q = 0; q < WV; ++q) v += vred[q][tid];
        atomicAdd(&ws[WS_VARSUMS + b * KK + tid], v);
    }
}

// ---------------- ABLATION 1: loads only, x8 reps ----------------------------
// Measures the pure memory path (data + labels) with zero accumulate work.
__global__ __launch_bounds__(T, 8) void abl1_ld(const float* __restrict__ data,
                                                const int* __restrict__ labels,
                                                float* __restrict__ ws) {
    const int e    = blockIdx.x;
    const int b    = e & 7;
    const int rem  = e >> 3;
    const int d    = rem & 15;
    const int sb   = rem >> 4;
    const int tid  = threadIdx.x;
    const int wv   = tid >> 6;
    const int lane = tid & 63;

    const float4* dpl = (const float4*)(data + ((size_t)b * DD + d) * NN);
    const int4*   lp4 = (const int4*)(labels + (size_t)b * NN);
    const int gbase = sb * 4096 + wv * 1024 + lane;

    for (int rep = 0; rep < 8; ++rep) {
        asm volatile("" ::: "memory");   // force re-load each rep
#pragma unroll 4
        for (int i = 0; i < 16; ++i) {
            const int g = gbase + i * 64;
            float4 x  = dpl[g];
            int4   lb = lp4[g];
            asm volatile("" :: "v"(x.x), "v"(x.y), "v"(x.z), "v"(x.w));
            asm volatile("" :: "v"(lb.x), "v"(lb.y), "v"(lb.z), "v"(lb.w));
        }
    }
    if (tid == 0) ws[WS_DUMP + (e & 63)] = 1.0f;
}

// ---------------- ABLATION 2: data loads + synthetic-label RMW, x8 ----------
// No label loads; bucket index rotates deterministically (distinct per p, no
// same-address chains, fixed bank pattern). Isolates DS-RMW mechanics.
__global__ __launch_bounds__(T, 8) void abl2_nolab(const float* __restrict__ data,
                                                   float* __restrict__ ws) {
    const int e    = blockIdx.x;
    const int b    = e & 7;
    const int rem  = e >> 3;
    const int d    = rem & 15;
    const int sb   = rem >> 4;
    const int tid  = threadIdx.x;
    const int wv   = tid >> 6;
    const int lane = tid & 63;

    __shared__ float buck[T * 9];
    float* mybuck = &buck[tid * 9];
#pragma unroll
    for (int k = 0; k < KK; ++k) mybuck[k] = 0.f;

    const float4* dpl = (const float4*)(data + ((size_t)b * DD + d) * NN);
    const int gbase = sb * 4096 + wv * 1024 + lane;

    for (int rep = 0; rep < 8; ++rep) {
        asm volatile("" ::: "memory");
#pragma unroll 4
        for (int i = 0; i < 16; ++i) {
            const int g = gbase + i * 64;
            float4 x = dpl[g];
            mybuck[(lane + i + 0) & 7] += x.x;
            mybuck[(lane + i + 1) & 7] += x.y;
            mybuck[(lane + i + 2) & 7] += x.z;
            mybuck[(lane + i + 3) & 7] += x.w;
        }
    }
    if (tid < KK) {
        float v = mybuck[tid];
        atomicAdd(&ws[WS_DUMP + (b * KK + tid) * DD + d], v);
    }
}

// ---------------- ABLATION 3: full round-10 body, x8 reps -------------------
__global__ __launch_bounds__(T, 8) void abl3_full(const float* __restrict__ data,
                                                  const int* __restrict__ labels,
                                                  float* __restrict__ ws) {
    const int e    = blockIdx.x;
    const int b    = e & 7;
    const int rem  = e >> 3;
    const int d    = rem & 15;
    const int sb   = rem >> 4;
    const int tid  = threadIdx.x;
    const int wv   = tid >> 6;
    const int lane = tid & 63;

    __shared__ float buck[T * 9];
    float* mybuck = &buck[tid * 9];
#pragma unroll
    for (int k = 0; k < KK; ++k) mybuck[k] = 0.f;

    const float4* dpl = (const float4*)(data + ((size_t)b * DD + d) * NN);
    const int4*   lp4 = (const int4*)(labels + (size_t)b * NN);
    const int gbase = sb * 4096 + wv * 1024 + lane;

    float c[KK];
#pragma unroll
    for (int k = 0; k < KK; ++k) c[k] = 0.f;

    for (int rep = 0; rep < 8; ++rep) {
        asm volatile("" ::: "memory");
#pragma unroll 4
        for (int i = 0; i < 16; ++i) {
            const int g = gbase + i * 64;
            float4 x  = dpl[g];
            int4   lb = lp4[g];
            mybuck[lb.x] += x.x;
            mybuck[lb.y] += x.y;
            mybuck[lb.z] += x.z;
            mybuck[lb.w] += x.w;
            if (d == 0) {
                int labs[4] = {lb.x, lb.y, lb.z, lb.w};
#pragma unroll
                for (int p = 0; p < 4; ++p) {
                    const int l = labs[p];
#pragma unroll
                    for (int k = 0; k < KK; ++k)
                        c[k] += (l == k) ? 1.f : 0.f;
                }
            }
        }
    }
    float s0 = 0.f;
#pragma unroll
    for (int k = 0; k < KK; ++k) s0 += mybuck[k] + c[k];
    if (tid < KK) atomicAdd(&ws[WS_DUMP + (b * KK + tid) * DD + d], s0);
}

// ---------------- Final (REAL, identical to round 10) -----------------------
__global__ void k_final(const float* __restrict__ ws, float* __restrict__ out) {
    const int t = threadIdx.x;
    const int b = t >> 3, k = t & 7;
    const float inv = 1.0f / ws[WS_CNTS + t];
    __shared__ float sc[BB * KK][DD];
    float cen[DD];
    float n2 = 0.f;
#pragma unroll
    for (int d = 0; d < DD; ++d) {
        float v = ws[WS_SUMS + t * DD + d] * inv;
        cen[d] = v;
        sc[t][d] = v;
        n2 = fmaf(v, v, n2);
    }
    __syncthreads();
    float rg = fmaxf(sqrtf(n2) - 4.0f, 0.f);
    rg *= rg;
    float rowcost = 0.f;
#pragma unroll
    for (int j = 0; j < KK; ++j) {
        float d2 = 0.f;
#pragma unroll
        for (int d = 0; d < DD; ++d) {
            float df = cen[d] - sc[b * KK + j][d];
            d2 = fmaf(df, df, d2);
        }
        float dm = sqrtf(d2) + ((j == k) ? 2.0f : 0.0f);
        float h = fmaxf(2.0f - dm, 0.f);
        rowcost += h * h;
    }
    float var  = ws[WS_VARSUMS + t] * inv;
    float term = var / (float)KK + rowcost / 56.0f + rg / (float)KK;
#pragma unroll
    for (int m = 1; m < 64; m <<= 1) term += __shfl_xor(term, m, 64);
    if (t == 0) out[0] = term / (float)BB;
}

extern "C" void kernel_launch(void* const* d_in, const int* in_sizes, int n_in,
                              void* d_out, int out_size, void* d_ws, size_t ws_size,
                              hipStream_t stream) {
    const float* data   = (const float*)d_in[0];
    const int*   labels = (const int*)d_in[1];
    float*       ws     = (float*)d_ws;

    hipMemsetAsync(d_ws, 0, WS_TOTAL * sizeof(float), stream);
    k_sums<<<2048, T, 0, stream>>>(data, labels, ws);
    k_var<<<BB * VBPB, T, 0, stream>>>(data, labels, ws);
    // ---- ablation probes (outputs dumped, never read) ----
    abl1_ld<<<2048, T, 0, stream>>>(data, labels, ws);
    abl2_nolab<<<2048, T, 0, stream>>>(data, ws);
    abl3_full<<<2048, T, 0, stream>>>(data, labels, ws);
    k_final<<<1, 64, 0, stream>>>(ws, (float*)d_out);
}

// Round 14
// 226.135 us; speedup vs baseline: 3.0986x; 3.0986x over previous
//
#include <hip/hip_runtime.h>
#include <hip/hip_bf16.h>

// Problem constants: B=8, d=16, H=W=512, K=8
#define BB 8
#define DD 16
#define KK 8
#define NN (512 * 512)
#define G4 (NN / 4)               // 65536 float4-groups per (b,d) plane

constexpr int T    = 256;         // threads per block (4 waves)
constexpr int WV   = 4;           // waves per block
constexpr int VBPB = 128;         // k_var blocks per batch -> grid = 1024

typedef float __attribute__((ext_vector_type(4))) f4;
typedef int   __attribute__((ext_vector_type(4))) i4;

// ws layout (floats):
#define WS_SUMS    0      // [B][K][D]  (atomics, zeroed)
#define WS_CNTS    1024   // [B][K]
#define WS_VARSUMS 1088   // [B][K]
#define WS_TOTAL   1152

// ---------------- Pass 1: per-(b,k) sums and counts -------------------------
// Identical to round 10 except loads are NON-TEMPORAL: the harness's 512-MiB
// ws poison leaves ~256 MB dirty in the Infinity Cache; normal read-misses
// evict those dirty lines (HBM writeback storm -> ~2 TB/s effective). nt
// loads avoid allocating / mark our lines evict-first, so victims are our own
// clean lines, not dirty poison -> reads run at HBM BW.
__global__ __launch_bounds__(T, 8) void k_sums(const float* __restrict__ data,
                                               const int* __restrict__ labels,
                                               float* __restrict__ ws) {
    const int e    = blockIdx.x;
    const int b    = e & 7;            // XCD-pinned batch
    const int rem  = e >> 3;
    const int d    = rem & 15;         // dim plane
    const int sb   = rem >> 4;         // segment-block within plane
    const int tid  = threadIdx.x;
    const int wv   = tid >> 6;
    const int lane = tid & 63;

    __shared__ float buck[T * 9];      // thread-private buckets, stride 9
    float* mybuck = &buck[tid * 9];
#pragma unroll
    for (int k = 0; k < KK; ++k) mybuck[k] = 0.f;

    const f4* dpl = (const f4*)(data + ((size_t)b * DD + d) * NN);
    const i4* lp4 = (const i4*)(labels + (size_t)b * NN);
    const int gbase = sb * 4096 + wv * 1024 + lane;

    float c[KK];
#pragma unroll
    for (int k = 0; k < KK; ++k) c[k] = 0.f;

#pragma unroll 4
    for (int i = 0; i < 16; ++i) {
        const int g = gbase + i * 64;
        f4 x  = __builtin_nontemporal_load(dpl + g);   // 1 KB contiguous/wave
        i4 lb = __builtin_nontemporal_load(lp4 + g);
        mybuck[lb.x] += x.x;
        mybuck[lb.y] += x.y;
        mybuck[lb.z] += x.z;
        mybuck[lb.w] += x.w;
        if (d == 0) {                  // counts: only 1/16 of blocks pay this
            int labs[4] = {lb.x, lb.y, lb.z, lb.w};
#pragma unroll
            for (int p = 0; p < 4; ++p) {
                const int l = labs[p];
#pragma unroll
                for (int k = 0; k < KK; ++k)
                    c[k] += (l == k) ? 1.f : 0.f;
            }
        }
    }

    float s[KK];
#pragma unroll
    for (int k = 0; k < KK; ++k) s[k] = mybuck[k];
#pragma unroll
    for (int k = 0; k < KK; ++k) {
#pragma unroll
        for (int m = 1; m < 64; m <<= 1) s[k] += __shfl_xor(s[k], m, 64);
    }
    if (d == 0) {
#pragma unroll
        for (int k = 0; k < KK; ++k) {
#pragma unroll
            for (int m = 1; m < 64; m <<= 1) c[k] += __shfl_xor(c[k], m, 64);
        }
    }

    __shared__ float sred[WV][KK];
    __shared__ float cred[WV][KK];
    if (lane == 0) {
#pragma unroll
        for (int k = 0; k < KK; ++k) { sred[wv][k] = s[k]; cred[wv][k] = c[k]; }
    }
    __syncthreads();

    if (tid < KK) {
        float v = sred[0][tid] + sred[1][tid] + sred[2][tid] + sred[3][tid];
        atomicAdd(&ws[WS_SUMS + (b * KK + tid) * DD + d], v);
    } else if (d == 0 && tid >= 64 && tid < 64 + KK) {
        const int k = tid - 64;
        float v = cred[0][k] + cred[1][k] + cred[2][k] + cred[3][k];
        atomicAdd(&ws[WS_CNTS + b * KK + k], v);
    }
}

// ---------------- Pass 2: variance term (plane-major, nt loads) -------------
__global__ __launch_bounds__(T, 4) void k_var(const float* __restrict__ data,
                                              const int* __restrict__ labels,
                                              float* __restrict__ ws) {
    const int b   = blockIdx.x / VBPB;
    const int blk = blockIdx.x % VBPB;
    const int tid = threadIdx.x;

    __shared__ float cs[KK * 17 + DD];   // centers, stride-17 (conflict-free)
    if (tid < KK * DD) {
        const int k = tid >> 4, d = tid & 15;
        cs[k * 17 + d] = ws[WS_SUMS + (b * KK + k) * DD + d] / ws[WS_CNTS + b * KK + k];
    }
    __syncthreads();

    const f4* dp4 = (const f4*)(data + (size_t)b * DD * NN);
    const i4* lp4 = (const i4*)(labels + (size_t)b * NN);
    const int g0 = blk * 512 + tid;      // first group
    const int g1 = g0 + 256;             // second group

    i4 lb0 = __builtin_nontemporal_load(lp4 + g0);
    i4 lb1 = __builtin_nontemporal_load(lp4 + g1);
    int l[8] = {lb0.x, lb0.y, lb0.z, lb0.w, lb1.x, lb1.y, lb1.z, lb1.w};
    float ss[8] = {0.f, 0.f, 0.f, 0.f, 0.f, 0.f, 0.f, 0.f};

#pragma unroll 4
    for (int d = 0; d < DD; ++d) {
        const f4* pl = dp4 + (size_t)d * G4;
        f4 x0 = __builtin_nontemporal_load(pl + g0);   // 1 KB contiguous/wave
        f4 x1 = __builtin_nontemporal_load(pl + g1);
        float xs[8] = {x0.x, x0.y, x0.z, x0.w, x1.x, x1.y, x1.z, x1.w};
#pragma unroll
        for (int p = 0; p < 8; ++p) {
            float c  = cs[l[p] * 17 + d];
            float df = xs[p] - c;
            ss[p] = fmaf(df, df, ss[p]);
        }
    }

    float acc[KK];
#pragma unroll
    for (int k = 0; k < KK; ++k) acc[k] = 0.f;
#pragma unroll
    for (int p = 0; p < 8; ++p) {
        float e  = fmaxf(sqrtf(ss[p]) - 1.0f, 0.f);   // DELTA_VAR = 1
        float e2 = e * e;
#pragma unroll
        for (int k = 0; k < KK; ++k) acc[k] += (l[p] == k) ? e2 : 0.f;
    }

    const int lane = tid & 63, wv = tid >> 6;
#pragma unroll
    for (int k = 0; k < KK; ++k) {
#pragma unroll
        for (int m = 1; m < 64; m <<= 1) acc[k] += __shfl_xor(acc[k], m, 64);
    }
    __shared__ float vred[WV][KK];
    if (lane == 0) {
#pragma unroll
        for (int k = 0; k < KK; ++k) vred[wv][k] = acc[k];
    }
    __syncthreads();
    if (tid < KK) {
        float v = 0.f;
#pragma unroll
        for (int q = 0; q < WV; ++q) v += vred[q][tid];
        atomicAdd(&ws[WS_VARSUMS + b * KK + tid], v);
    }
}

// ---------------- Final: centers + dist/reg/var combine ---------------------
__global__ void k_final(const float* __restrict__ ws, float* __restrict__ out) {
    const int t = threadIdx.x;           // 0..63 : b = t>>3, k = t&7
    const int b = t >> 3, k = t & 7;
    const float inv = 1.0f / ws[WS_CNTS + t];
    __shared__ float sc[BB * KK][DD];
    float cen[DD];
    float n2 = 0.f;
#pragma unroll
    for (int d = 0; d < DD; ++d) {
        float v = ws[WS_SUMS + t * DD + d] * inv;
        cen[d] = v;
        sc[t][d] = v;
        n2 = fmaf(v, v, n2);
    }
    __syncthreads();
    float rg = fmaxf(sqrtf(n2) - 4.0f, 0.f);   // delta_reg = sqrt(16) = 4
    rg *= rg;
    float rowcost = 0.f;
#pragma unroll
    for (int j = 0; j < KK; ++j) {
        float d2 = 0.f;
#pragma unroll
        for (int d = 0; d < DD; ++d) {
            float df = cen[d] - sc[b * KK + j][d];
            d2 = fmaf(df, df, d2);
        }
        float dm = sqrtf(d2) + ((j == k) ? 2.0f : 0.0f);   // eye*DELTA_DIST trick
        float h = fmaxf(2.0f - dm, 0.f);
        rowcost += h * h;
    }
    float var  = ws[WS_VARSUMS + t] * inv;
    float term = var / (float)KK + rowcost / 56.0f + rg / (float)KK;
#pragma unroll
    for (int m = 1; m < 64; m <<= 1) term += __shfl_xor(term, m, 64);
    if (t == 0) out[0] = term / (float)BB;
}

extern "C" void kernel_launch(void* const* d_in, const int* in_sizes, int n_in,
                              void* d_out, int out_size, void* d_ws, size_t ws_size,
                              hipStream_t stream) {
    const float* data   = (const float*)d_in[0];
    const int*   labels = (const int*)d_in[1];
    float*       ws     = (float*)d_ws;

    hipMemsetAsync(d_ws, 0, WS_TOTAL * sizeof(float), stream);
    k_sums<<<2048, T, 0, stream>>>(data, labels, ws);
    k_var<<<BB * VBPB, T, 0, stream>>>(data, labels, ws);
    k_final<<<1, 64, 0, stream>>>(ws, (float*)d_out);
}